// Round 12
// baseline (266.572 us; speedup 1.0000x reference)
//
#include <hip/hip_runtime.h>
#include <hip/hip_bf16.h>
#include <hip/hip_fp16.h>

#define NB 128      // batch
#define NT 128      // Tm1
#define ND 128      // input size (drivers)
#define NH 64       // hidden
#define NTH 1024    // threads per block
#define ESTR 144    // Ebt row stride (ushorts)

typedef float f32x2 __attribute__((ext_vector_type(2)));
typedef _Float16 f16x2 __attribute__((ext_vector_type(2)));

__device__ __forceinline__ float fexp2(float x) { return __builtin_amdgcn_exp2f(x); }
__device__ __forceinline__ float frcp (float x) { return __builtin_amdgcn_rcpf(x); }

template<int CTRL>
__device__ __forceinline__ float dppadd(float v) {
  return v + __int_as_float(__builtin_amdgcn_update_dpp(
      0, __float_as_int(v), CTRL, 0xF, 0xF, true));
}
__device__ __forceinline__ float sum16(float v) {
  v = dppadd<0xB1>(v);   // quad_perm [1,0,3,2]
  v = dppadd<0x4E>(v);   // quad_perm [2,3,0,1]
  v = dppadd<0x141>(v);  // row_half_mirror
  v = dppadd<0x140>(v);  // row_mirror
  return v;
}

// f32 -> bf16 bits, round-to-nearest-even
__device__ __forceinline__ unsigned short f2bf(float f) {
  unsigned u = __float_as_uint(f);
  u += 0x7fffu + ((u >> 16) & 1u);
  return (unsigned short)(u >> 16);
}
__device__ __forceinline__ float blo(unsigned u) { return __uint_as_float(u << 16); }
__device__ __forceinline__ float bhi(unsigned u) { return __uint_as_float(u & 0xffff0000u); }

// u32 <-> __half2 bit casts
__device__ __forceinline__ __half2 uh(unsigned u) {
  union { unsigned u; __half2 h; } x; x.u = u; return x.h;
}
__device__ __forceinline__ unsigned hu(__half2 h) {
  union { unsigned u; __half2 h; } x; x.h = h; return x.u;
}
__device__ __forceinline__ f16x2 uh2(unsigned u) {
  union { unsigned u; f16x2 h; } x; x.u = u; return x.h;
}
__device__ __forceinline__ unsigned pkf16(float lo, float hi) {
  return hu(__halves2half2(__float2half_rn(lo), __float2half_rn(hi)));
}

// 2-way f16 dot with f32 accumulate: v_dot2_f32_f16 (no unpack glue)
__device__ __forceinline__ float dot2(unsigned a, unsigned b, float c) {
#if __has_builtin(__builtin_amdgcn_fdot2)
  return __builtin_amdgcn_fdot2(uh2(a), uh2(b), c, false);
#else
  const __half2 p = __hmul2(uh(a), uh(b));
  return c + __low2float(p) + __high2float(p);
#endif
}

#define PIN(v) asm volatile("" : "+v"(v))

__global__ __launch_bounds__(NTH)
__attribute__((amdgpu_waves_per_eu(4, 4)))
void darnn_enc(
    const float* __restrict__ x,     // [B][T1][D]
    const float* __restrict__ Wehs,  // [T1][2H]
    const float* __restrict__ behs,  // [T1]
    const float* __restrict__ Ue,    // [T1][T1]
    const float* __restrict__ Ueb,   // [T1]
    const float* __restrict__ vew,   // [T1]
    const float* __restrict__ Wih,   // [4H][D]
    const float* __restrict__ Whh,   // [4H][H]
    const float* __restrict__ bih,   // [256]
    const float* __restrict__ bhh,   // [256]
    float* __restrict__ out)
{
  constexpr float C2  = 2.88539008177792681f;  // 2*log2(e)
  constexpr float L2E = 1.44269504088896340f;  // log2(e)

  __shared__ __align__(16) float          xh[NT][ND];     // 64K: x, overwritten by e*x
  __shared__ __align__(16) unsigned short Ebt[ND][ESTR];  // 36.9K: E bf16 (prologue)
  __shared__ __align__(16) float          hbuf[NT][NH];   // 32K: h outputs (prologue: UeTc)
  __shared__ __align__(16) unsigned       hcpk[2][8][12]; // [h|c] as half2, dbuf
  __shared__ __align__(16) float          cq[2][16][6];   // c f32 (cell state), dbuf
  __shared__ __align__(16) float          wvm[16][12];    // w_s (L2E-prefolded), 8/row
  __shared__ __align__(16) unsigned       xpk[16][12];    // e*x as half2, 8 vals/row
  __shared__ __align__(16) float          part64[64];     // per-d-pair partial sums of e
  __shared__ __align__(16) float          rsb[NT];        // 1/sum(e) per step

  const int b    = blockIdx.x;
  const int tid  = threadIdx.x;
  const int lane = tid & 63;
  const int wid  = tid >> 6;
  const float* xb = x + b * (NT * ND);

  // ---------------- stage x into LDS ---------------------------------------
#pragma unroll
  for (int i = 0; i < 4; ++i) {
    const int f = i * 1024 + tid;
    const int t = f >> 5, c = (f & 31) << 2;
    *reinterpret_cast<float4*>(&xh[t][c]) =
        *reinterpret_cast<const float4*>(xb + t * ND + c);
  }
  float (*UeTc)[33] = reinterpret_cast<float(*)[33]>(&hbuf[0][0]);
  __syncthreads();

  // ---------------- Prologue: E[d][s] = exp(2*(x_perm @ Ue^T + Ueb)) --------
  {
    const int dq = tid & 31;
    const int sg = tid >> 5;
    float acc[16];
#pragma unroll
    for (int i = 0; i < 16; ++i) acc[i] = 0.f;
    for (int c = 0; c < 4; ++c) {
      {
        const int ss = 32 * c + sg;
        const int t4 = dq * 4;
        const float4 u4 = *reinterpret_cast<const float4*>(Ue + ss * NT + t4);
        UeTc[t4 + 0][sg] = u4.x;
        UeTc[t4 + 1][sg] = u4.y;
        UeTc[t4 + 2][sg] = u4.z;
        UeTc[t4 + 3][sg] = u4.w;
      }
      __syncthreads();
#pragma unroll 4
      for (int t = 0; t < NT; ++t) {
        const float4 xv = *reinterpret_cast<const float4*>(&xh[t][4 * dq]);
        const float u = UeTc[t][sg];
        acc[4*c+0] = fmaf(xv.x, u, acc[4*c+0]);
        acc[4*c+1] = fmaf(xv.y, u, acc[4*c+1]);
        acc[4*c+2] = fmaf(xv.z, u, acc[4*c+2]);
        acc[4*c+3] = fmaf(xv.w, u, acc[4*c+3]);
      }
      __syncthreads();
    }
#pragma unroll
    for (int c = 0; c < 4; ++c) {
      const int ss = sg + 32 * c;
      const float ub = Ueb[ss];
#pragma unroll
      for (int di = 0; di < 4; ++di) {
        const float e = fexp2(C2 * (acc[4*c+di] + ub));
        Ebt[4*dq + di][ss] = f2bf(e);
      }
    }
  }
  __syncthreads();   // Ebt complete before register loads

  // zero h/c state (both parities)
  if (tid < 192) (&hcpk[0][0][0])[tid] = 0u;          // half2(0,0)
  if (tid < 192) (&cq[0][0][0])[tid] = 0.f;

  // ---------------- persistent per-thread registers -------------------------
  // phase A: 8 threads per s; C2 folded into weights/bias -> exp2 arg direct
  const int s_a = tid >> 3, r_a = tid & 7;
  unsigned wehs_p[8];
#pragma unroll
  for (int i = 0; i < 4; ++i) {
    const float4 v4 = *reinterpret_cast<const float4*>(Wehs + s_a * 128 + r_a * 16 + 4 * i);
    wehs_p[2*i]   = pkf16(C2 * v4.x, C2 * v4.y);
    wehs_p[2*i+1] = pkf16(C2 * v4.z, C2 * v4.w);
  }
  float behs_r = C2 * behs[s_a];

  // phase B: lane = s_l + 16*dp; d0 = 8*wid + 2*dp; L2E folded into mv
  const int s_l = lane & 15;
  const int dp  = lane >> 4;
  const int d0  = 8 * wid + 2 * dp;
  f32x2 mv[4];
  {
    const float4 va = *reinterpret_cast<const float4*>(vew + 8 * s_l);
    const float4 vb = *reinterpret_cast<const float4*>(vew + 8 * s_l + 4);
    const float k = -2.f * L2E;
    mv[0] = (f32x2){k * va.x, k * va.y};
    mv[1] = (f32x2){k * va.z, k * va.w};
    mv[2] = (f32x2){k * vb.x, k * vb.y};
    mv[3] = (f32x2){k * vb.z, k * vb.w};
  }
  // E fragments as f32 pairs (time-invariant, pre-unpacked from bf16)
  f32x2 er2[8];
  {
    const int4 ea = *reinterpret_cast<const int4*>(&Ebt[d0][8 * s_l]);
    const int4 eb = *reinterpret_cast<const int4*>(&Ebt[d0 + 1][8 * s_l]);
    er2[0] = (f32x2){blo((unsigned)ea.x), bhi((unsigned)ea.x)};
    er2[1] = (f32x2){blo((unsigned)ea.y), bhi((unsigned)ea.y)};
    er2[2] = (f32x2){blo((unsigned)ea.z), bhi((unsigned)ea.z)};
    er2[3] = (f32x2){blo((unsigned)ea.w), bhi((unsigned)ea.w)};
    er2[4] = (f32x2){blo((unsigned)eb.x), bhi((unsigned)eb.x)};
    er2[5] = (f32x2){blo((unsigned)eb.y), bhi((unsigned)eb.y)};
    er2[6] = (f32x2){blo((unsigned)eb.z), bhi((unsigned)eb.z)};
    er2[7] = (f32x2){blo((unsigned)eb.w), bhi((unsigned)eb.w)};
  }

  // phase D+E: lane = 16*kk + cD; unit kD = 4*wid + kk; 4 gates per lane
  const int kk = lane >> 4, cD = lane & 15;
  const int kD = 4 * wid + kk;
  unsigned wx2[16], wh2[8];   // half2-packed gate weights
  float b4[4];
#pragma unroll
  for (int g = 0; g < 4; ++g) {
    const int j = 64 * g + kD;
    const float4 u0 = *reinterpret_cast<const float4*>(Wih + j * 128 + 8 * cD);
    const float4 u1 = *reinterpret_cast<const float4*>(Wih + j * 128 + 8 * cD + 4);
    wx2[4*g]   = pkf16(u0.x, u0.y);
    wx2[4*g+1] = pkf16(u0.z, u0.w);
    wx2[4*g+2] = pkf16(u1.x, u1.y);
    wx2[4*g+3] = pkf16(u1.z, u1.w);
    const float4 u2 = *reinterpret_cast<const float4*>(Whh + j * 64 + 4 * cD);
    wh2[2*g]   = pkf16(u2.x, u2.y);
    wh2[2*g+1] = pkf16(u2.z, u2.w);
    b4[g] = bih[j] + bhh[j];
  }

#pragma unroll
  for (int i = 0; i < 8; ++i) PIN(wehs_p[i]);
#pragma unroll
  for (int i = 0; i < 8; ++i) PIN(er2[i]);
#pragma unroll
  for (int i = 0; i < 4; ++i) PIN(mv[i]);
#pragma unroll
  for (int i = 0; i < 16; ++i) PIN(wx2[i]);
#pragma unroll
  for (int i = 0; i < 8; ++i) PIN(wh2[i]);
#pragma unroll
  for (int g = 0; g < 4; ++g) PIN(b4[g]);
  PIN(behs_r);

  __syncthreads();

  // ---------------- main recurrence: unrolled x2, compile-time parity -------
#define STEP(T, P) do {                                                        \
    /* x_t pair: only the s_l==0 writer lanes need it (kills 4-way conflict) */\
    float2 xv = make_float2(0.f, 0.f);                                         \
    if (s_l == 0) xv = *reinterpret_cast<const float2*>(&xh[(T)][d0]);         \
    float c_old;                                                               \
    /* A: w[s] = exp2(C2*(h.W+b)) — C2 prefolded */ {                          \
      const int4 q0 = *reinterpret_cast<const int4*>(&hcpk[(P)][r_a][0]);      \
      const int4 q1 = *reinterpret_cast<const int4*>(&hcpk[(P)][r_a][4]);      \
      c_old = cq[(P)][wid][kk];   /* D's input, stable since D(t-1) barrier */ \
      float a0 = 0.f, a1 = 0.f;                                                \
      a0 = dot2((unsigned)q0.x, wehs_p[0], a0);                                \
      a1 = dot2((unsigned)q0.y, wehs_p[1], a1);                                \
      a0 = dot2((unsigned)q0.z, wehs_p[2], a0);                                \
      a1 = dot2((unsigned)q0.w, wehs_p[3], a1);                                \
      a0 = dot2((unsigned)q1.x, wehs_p[4], a0);                                \
      a1 = dot2((unsigned)q1.y, wehs_p[5], a1);                                \
      a0 = dot2((unsigned)q1.z, wehs_p[6], a0);                                \
      a1 = dot2((unsigned)q1.w, wehs_p[7], a1);                                \
      float a = a0 + a1;                                                       \
      a = dppadd<0xB1>(a);                                                     \
      a = dppadd<0x4E>(a);                                                     \
      a = dppadd<0x141>(a);                                                    \
      if (r_a == 0) wvm[s_a >> 3][s_a & 7] = fexp2(a + behs_r);                \
    }                                                                          \
    __syncthreads();                                                           \
    int2 hh;                                                                   \
    /* B: e[d] = exp2(L2E*v) — L2E prefolded into mv */ {                      \
      const float4 wa = *reinterpret_cast<const float4*>(&wvm[s_l][0]);        \
      const float4 wb = *reinterpret_cast<const float4*>(&wvm[s_l][4]);        \
      hh = *reinterpret_cast<const int2*>(&hcpk[(P)][cD >> 2][2 * (cD & 3)]);  \
      const f32x2 one2 = {1.f, 1.f};                                           \
      const f32x2 w01 = {wa.x, wa.y}, w23 = {wa.z, wa.w};                      \
      const f32x2 w45 = {wb.x, wb.y}, w67 = {wb.z, wb.w};                      \
      f32x2 ac0 = {0.f, 0.f}, ac0b = {0.f, 0.f};                               \
      f32x2 ac1 = {0.f, 0.f}, ac1b = {0.f, 0.f};                               \
      BSTEP(w01, er2[0], mv[0], ac0);                                          \
      BSTEP(w23, er2[1], mv[1], ac0b);                                         \
      BSTEP(w45, er2[2], mv[2], ac0);                                          \
      BSTEP(w67, er2[3], mv[3], ac0b);                                         \
      BSTEP(w01, er2[4], mv[0], ac1);                                          \
      BSTEP(w23, er2[5], mv[1], ac1b);                                         \
      BSTEP(w45, er2[6], mv[2], ac1);                                          \
      BSTEP(w67, er2[7], mv[3], ac1b);                                         \
      const f32x2 sv0 = ac0 + ac0b;                                            \
      const f32x2 sv1 = ac1 + ac1b;                                            \
      float s0 = sum16(sv0.x + sv0.y);                                         \
      float s1 = sum16(sv1.x + sv1.y);                                         \
      const float e0 = fexp2(s0);                                              \
      const float e1 = fexp2(s1);                                              \
      if (s_l == 0) {                                                          \
        part64[4 * wid + dp] = e0 + e1;                                        \
        xpk[wid][dp] = pkf16(e0 * xv.x, e1 * xv.y);                            \
        *reinterpret_cast<float2*>(&xh[(T)][d0]) =                             \
            make_float2(e0 * xv.x, e1 * xv.y);                                 \
      }                                                                        \
    }                                                                          \
    __syncthreads();                                                           \
    /* D+E: gate dot2 first (no rs dependency), Σe reduce in parallel */ {     \
      const int4 xq = *reinterpret_cast<const int4*>(&xpk[cD][0]);             \
      float sx[4], sh[4];                                                      \
      _Pragma("unroll")                                                        \
      for (int g = 0; g < 4; ++g) {                                            \
        float s = 0.f;                                                         \
        s = dot2((unsigned)xq.x, wx2[4*g],   s);                               \
        s = dot2((unsigned)xq.y, wx2[4*g+1], s);                               \
        s = dot2((unsigned)xq.z, wx2[4*g+2], s);                               \
        s = dot2((unsigned)xq.w, wx2[4*g+3], s);                               \
        sx[g] = s;                                                             \
        float h = 0.f;                                                         \
        h = dot2((unsigned)hh.x, wh2[2*g],   h);                               \
        h = dot2((unsigned)hh.y, wh2[2*g+1], h);                               \
        sh[g] = h;                                                             \
      }                                                                        \
      float tot = part64[lane];                                                \
      tot = sum16(tot);                                                        \
      tot += __int_as_float(__builtin_amdgcn_ds_swizzle(__float_as_int(tot), 0x401F)); \
      tot += __shfl_xor(tot, 32);                                              \
      const float rs = frcp(tot);                                              \
      float ac[4];                                                             \
      _Pragma("unroll")                                                        \
      for (int g = 0; g < 4; ++g) ac[g] = sum16(fmaf(sx[g], rs, sh[g]));       \
      const float gi = ac[0] + b4[0];                                          \
      const float gf = ac[1] + b4[1];                                          \
      const float gG = ac[2] + b4[2];                                          \
      const float go = ac[3] + b4[3];                                          \
      const float si = frcp(1.f + fexp2(-L2E * gi));                           \
      const float sf = frcp(1.f + fexp2(-L2E * gf));                           \
      const float tg = 1.f - 2.f * frcp(1.f + fexp2(C2 * gG));                 \
      const float cn = fmaf(sf, c_old, si * tg);                               \
      const float so = frcp(1.f + fexp2(-L2E * go));                           \
      const float tc = 1.f - 2.f * frcp(1.f + fexp2(C2 * cn));                 \
      const float hn = so * tc;                                                \
      if (cD == 0) {                                                           \
        __half* Hb = reinterpret_cast<__half*>(&hcpk[(P) ^ 1][0][0]);          \
        Hb[(kD >> 4) * 24 + (kD & 15)]       = __float2half_rn(hn);            \
        Hb[(4 + (kD >> 4)) * 24 + (kD & 15)] = __float2half_rn(cn);            \
        cq[(P) ^ 1][wid][kk] = cn;                                             \
        hbuf[(T)][kD] = hn;                                                    \
      }                                                                        \
      if (tid == 0) rsb[(T)] = rs;                                             \
    }                                                                          \
    __syncthreads();                                                           \
  } while (0)

#define BSTEP(W, E, M, ACC) do {                                   \
    f32x2 q_ = __builtin_elementwise_fma(W, E, one2);              \
    f32x2 r_; r_.x = frcp(q_.x); r_.y = frcp(q_.y);                \
    ACC = __builtin_elementwise_fma(M, r_, ACC);                   \
  } while (0)

  for (int t = 0; t < NT; t += 2) {
    STEP(t, 0);
    STEP(t + 1, 1);
  }
#undef BSTEP
#undef STEP

  // ---------------- bulk flush of outputs -----------------------------------
#pragma unroll
  for (int i = 0; i < 4; ++i) {
    const int f = i * 1024 + tid;
    const int t = f >> 5, c = (f & 31) << 2;
    float4 v = *reinterpret_cast<const float4*>(&xh[t][c]);
    const float rs = rsb[t];
    v.x *= rs; v.y *= rs; v.z *= rs; v.w *= rs;
    *reinterpret_cast<float4*>(out + b * (NT * ND) + t * ND + c) = v;
  }
  float* out2 = out + NB * (NT * ND) + b * (NT * NH);
#pragma unroll
  for (int i = 0; i < 2; ++i) {
    const int f = i * 1024 + tid;
    const int t = f >> 4, c = (f & 15) << 2;
    *reinterpret_cast<float4*>(out2 + t * NH + c) =
        *reinterpret_cast<const float4*>(&hbuf[t][c]);
  }
}

extern "C" void kernel_launch(void* const* d_in, const int* in_sizes, int n_in,
                              void* d_out, int out_size, void* d_ws, size_t ws_size,
                              hipStream_t stream) {
  const float* x    = (const float*)d_in[0];
  const float* Wehs = (const float*)d_in[1];
  const float* behs = (const float*)d_in[2];
  const float* Ue   = (const float*)d_in[3];
  const float* Ueb  = (const float*)d_in[4];
  const float* vew  = (const float*)d_in[5];
  // d_in[6] = v_e_b: constant shift before softmax -> no effect, unused.
  const float* Wih  = (const float*)d_in[7];
  const float* Whh  = (const float*)d_in[8];
  const float* bih  = (const float*)d_in[9];
  const float* bhh  = (const float*)d_in[10];
  float* out = (float*)d_out;

  darnn_enc<<<NB, NTH, 0, stream>>>(x, Wehs, behs, Ue, Ueb, vew, Wih, Whh, bih, bhh, out);
}

// Round 13
// 258.695 us; speedup vs baseline: 1.0304x; 1.0304x over previous
//
#include <hip/hip_runtime.h>
#include <hip/hip_bf16.h>
#include <hip/hip_fp16.h>

#define NB 128      // batch
#define NT 128      // Tm1
#define ND 128      // input size (drivers)
#define NH 64       // hidden
#define NTH 1024    // threads per block
#define ESTR 144    // Ebt row stride (ushorts)

typedef float f32x2 __attribute__((ext_vector_type(2)));
typedef _Float16 f16x2 __attribute__((ext_vector_type(2)));

__device__ __forceinline__ float fexp2(float x) { return __builtin_amdgcn_exp2f(x); }
__device__ __forceinline__ float frcp (float x) { return __builtin_amdgcn_rcpf(x); }

template<int CTRL>
__device__ __forceinline__ float dppadd(float v) {
  return v + __int_as_float(__builtin_amdgcn_update_dpp(
      0, __float_as_int(v), CTRL, 0xF, 0xF, true));
}
__device__ __forceinline__ float sum16(float v) {
  v = dppadd<0xB1>(v);   // quad_perm [1,0,3,2]
  v = dppadd<0x4E>(v);   // quad_perm [2,3,0,1]
  v = dppadd<0x141>(v);  // row_half_mirror
  v = dppadd<0x140>(v);  // row_mirror
  return v;
}

// f32 -> bf16 bits, round-to-nearest-even
__device__ __forceinline__ unsigned short f2bf(float f) {
  unsigned u = __float_as_uint(f);
  u += 0x7fffu + ((u >> 16) & 1u);
  return (unsigned short)(u >> 16);
}
__device__ __forceinline__ float blo(unsigned u) { return __uint_as_float(u << 16); }
__device__ __forceinline__ float bhi(unsigned u) { return __uint_as_float(u & 0xffff0000u); }

// u32 <-> __half2 bit casts
__device__ __forceinline__ __half2 uh(unsigned u) {
  union { unsigned u; __half2 h; } x; x.u = u; return x.h;
}
__device__ __forceinline__ unsigned hu(__half2 h) {
  union { unsigned u; __half2 h; } x; x.h = h; return x.u;
}
__device__ __forceinline__ f16x2 uh2(unsigned u) {
  union { unsigned u; f16x2 h; } x; x.u = u; return x.h;
}
__device__ __forceinline__ unsigned pkf16(float lo, float hi) {
  return hu(__halves2half2(__float2half_rn(lo), __float2half_rn(hi)));
}

// 2-way f16 dot with f32 accumulate: v_dot2_f32_f16 (no unpack glue)
__device__ __forceinline__ float dot2(unsigned a, unsigned b, float c) {
#if __has_builtin(__builtin_amdgcn_fdot2)
  return __builtin_amdgcn_fdot2(uh2(a), uh2(b), c, false);
#else
  const __half2 p = __hmul2(uh(a), uh(b));
  return c + __low2float(p) + __high2float(p);
#endif
}

#define PIN(v) asm volatile("" : "+v"(v))

__global__ __launch_bounds__(NTH)
__attribute__((amdgpu_waves_per_eu(4, 4)))
void darnn_enc(
    const float* __restrict__ x,     // [B][T1][D]
    const float* __restrict__ Wehs,  // [T1][2H]
    const float* __restrict__ behs,  // [T1]
    const float* __restrict__ Ue,    // [T1][T1]
    const float* __restrict__ Ueb,   // [T1]
    const float* __restrict__ vew,   // [T1]
    const float* __restrict__ Wih,   // [4H][D]
    const float* __restrict__ Whh,   // [4H][H]
    const float* __restrict__ bih,   // [256]
    const float* __restrict__ bhh,   // [256]
    float* __restrict__ out)
{
  constexpr float C2  = 2.88539008177792681f;  // 2*log2(e)
  constexpr float L2E = 1.44269504088896340f;  // log2(e)

  __shared__ __align__(16) float          xh[NT][ND];     // 64K: x, overwritten by e*x
  __shared__ __align__(16) unsigned short Ebt[ND][ESTR];  // 36.9K: E bf16 (prologue)
  __shared__ __align__(16) float          hbuf[NT][NH];   // 32K: h outputs (prologue: UeTc)
  __shared__ __align__(16) unsigned       hcpk[2][8][12]; // [h|c] as half2, dbuf
  __shared__ __align__(16) float          cq[2][16][6];   // c f32 (cell state), dbuf
  __shared__ __align__(16) float          wvm[16][12];    // w_s (L2E-prefolded), 8/row
  __shared__ __align__(16) unsigned       xpk[16][12];    // e*x as half2, 8 vals/row
  __shared__ __align__(16) float          part64[64];     // per-d-pair partial sums of e
  __shared__ __align__(16) float          rsb[NT];        // 1/sum(e) per step

  const int b    = blockIdx.x;
  const int tid  = threadIdx.x;
  const int lane = tid & 63;
  const int wid  = tid >> 6;
  const float* xb = x + b * (NT * ND);

  // ---------------- stage x into LDS ---------------------------------------
#pragma unroll
  for (int i = 0; i < 4; ++i) {
    const int f = i * 1024 + tid;
    const int t = f >> 5, c = (f & 31) << 2;
    *reinterpret_cast<float4*>(&xh[t][c]) =
        *reinterpret_cast<const float4*>(xb + t * ND + c);
  }
  float (*UeTc)[33] = reinterpret_cast<float(*)[33]>(&hbuf[0][0]);
  __syncthreads();

  // ---------------- Prologue: E[d][s] = exp(2*(x_perm @ Ue^T + Ueb)) --------
  // Role swap vs r1-r12: DQ = tid>>5 (d-quad), SQ = tid&31 (s in chunk).
  //  - xh[t][4*DQ] read: 2 distinct addrs/wave -> broadcast, conflict-free
  //  - UeTc[t][SQ]  read: stride-4B over 32 lanes -> conflict-free
  // (was: 4-way conflict on xh read = the constant 2.24M SQ_LDS_BANK_CONFLICT)
  {
    const int SQ = tid & 31;
    const int DQ = tid >> 5;
    float acc[16];
#pragma unroll
    for (int i = 0; i < 16; ++i) acc[i] = 0.f;
    for (int c = 0; c < 4; ++c) {
      {  // stage UeTc[t][s_local] = Ue[32c+s_local][t]; coalesced global read
        const int ss = 32 * c + DQ;
        const int t4 = 4 * SQ;
        const float4 u4 = *reinterpret_cast<const float4*>(Ue + ss * NT + t4);
        UeTc[t4 + 0][DQ] = u4.x;
        UeTc[t4 + 1][DQ] = u4.y;
        UeTc[t4 + 2][DQ] = u4.z;
        UeTc[t4 + 3][DQ] = u4.w;
      }
      __syncthreads();
#pragma unroll 4
      for (int t = 0; t < NT; ++t) {
        const float4 xv = *reinterpret_cast<const float4*>(&xh[t][4 * DQ]);
        const float u = UeTc[t][SQ];
        acc[4*c+0] = fmaf(xv.x, u, acc[4*c+0]);
        acc[4*c+1] = fmaf(xv.y, u, acc[4*c+1]);
        acc[4*c+2] = fmaf(xv.z, u, acc[4*c+2]);
        acc[4*c+3] = fmaf(xv.w, u, acc[4*c+3]);
      }
      __syncthreads();
    }
#pragma unroll
    for (int c = 0; c < 4; ++c) {
      const int ss = SQ + 32 * c;
      const float ub = Ueb[ss];
#pragma unroll
      for (int di = 0; di < 4; ++di) {
        const float e = fexp2(C2 * (acc[4*c+di] + ub));
        Ebt[4*DQ + di][ss] = f2bf(e);
      }
    }
  }
  __syncthreads();   // Ebt complete before register loads

  // zero h/c state (both parities)
  if (tid < 192) (&hcpk[0][0][0])[tid] = 0u;          // half2(0,0)
  if (tid < 192) (&cq[0][0][0])[tid] = 0.f;

  // ---------------- persistent per-thread registers -------------------------
  // phase A: 8 threads per s; C2 folded into weights/bias -> exp2 arg direct
  const int s_a = tid >> 3, r_a = tid & 7;
  unsigned wehs_p[8];
#pragma unroll
  for (int i = 0; i < 4; ++i) {
    const float4 v4 = *reinterpret_cast<const float4*>(Wehs + s_a * 128 + r_a * 16 + 4 * i);
    wehs_p[2*i]   = pkf16(C2 * v4.x, C2 * v4.y);
    wehs_p[2*i+1] = pkf16(C2 * v4.z, C2 * v4.w);
  }
  float behs_r = C2 * behs[s_a];

  // phase B: lane = s_l + 16*dp; d0 = 8*wid + 2*dp; L2E folded into mv
  const int s_l = lane & 15;
  const int dp  = lane >> 4;
  const int d0  = 8 * wid + 2 * dp;
  f32x2 mv[4];
  {
    const float4 va = *reinterpret_cast<const float4*>(vew + 8 * s_l);
    const float4 vb = *reinterpret_cast<const float4*>(vew + 8 * s_l + 4);
    const float k = -2.f * L2E;
    mv[0] = (f32x2){k * va.x, k * va.y};
    mv[1] = (f32x2){k * va.z, k * va.w};
    mv[2] = (f32x2){k * vb.x, k * vb.y};
    mv[3] = (f32x2){k * vb.z, k * vb.w};
  }
  // E fragments as f32 pairs (time-invariant, pre-unpacked from bf16)
  f32x2 er2[8];
  {
    const int4 ea = *reinterpret_cast<const int4*>(&Ebt[d0][8 * s_l]);
    const int4 eb = *reinterpret_cast<const int4*>(&Ebt[d0 + 1][8 * s_l]);
    er2[0] = (f32x2){blo((unsigned)ea.x), bhi((unsigned)ea.x)};
    er2[1] = (f32x2){blo((unsigned)ea.y), bhi((unsigned)ea.y)};
    er2[2] = (f32x2){blo((unsigned)ea.z), bhi((unsigned)ea.z)};
    er2[3] = (f32x2){blo((unsigned)ea.w), bhi((unsigned)ea.w)};
    er2[4] = (f32x2){blo((unsigned)eb.x), bhi((unsigned)eb.x)};
    er2[5] = (f32x2){blo((unsigned)eb.y), bhi((unsigned)eb.y)};
    er2[6] = (f32x2){blo((unsigned)eb.z), bhi((unsigned)eb.z)};
    er2[7] = (f32x2){blo((unsigned)eb.w), bhi((unsigned)eb.w)};
  }

  // phase D+E: lane = 16*kk + cD; unit kD = 4*wid + kk; 4 gates per lane
  const int kk = lane >> 4, cD = lane & 15;
  const int kD = 4 * wid + kk;
  unsigned wx2[16], wh2[8];   // half2-packed gate weights
  float b4[4];
#pragma unroll
  for (int g = 0; g < 4; ++g) {
    const int j = 64 * g + kD;
    const float4 u0 = *reinterpret_cast<const float4*>(Wih + j * 128 + 8 * cD);
    const float4 u1 = *reinterpret_cast<const float4*>(Wih + j * 128 + 8 * cD + 4);
    wx2[4*g]   = pkf16(u0.x, u0.y);
    wx2[4*g+1] = pkf16(u0.z, u0.w);
    wx2[4*g+2] = pkf16(u1.x, u1.y);
    wx2[4*g+3] = pkf16(u1.z, u1.w);
    const float4 u2 = *reinterpret_cast<const float4*>(Whh + j * 64 + 4 * cD);
    wh2[2*g]   = pkf16(u2.x, u2.y);
    wh2[2*g+1] = pkf16(u2.z, u2.w);
    b4[g] = bih[j] + bhh[j];
  }

#pragma unroll
  for (int i = 0; i < 8; ++i) PIN(wehs_p[i]);
#pragma unroll
  for (int i = 0; i < 8; ++i) PIN(er2[i]);
#pragma unroll
  for (int i = 0; i < 4; ++i) PIN(mv[i]);
#pragma unroll
  for (int i = 0; i < 16; ++i) PIN(wx2[i]);
#pragma unroll
  for (int i = 0; i < 8; ++i) PIN(wh2[i]);
#pragma unroll
  for (int g = 0; g < 4; ++g) PIN(b4[g]);
  PIN(behs_r);

  __syncthreads();

  // ---------------- main recurrence: unrolled x2, compile-time parity -------
#define STEP(T, P) do {                                                        \
    const float2 xv = *reinterpret_cast<const float2*>(&xh[(T)][d0]);          \
    float c_old;                                                               \
    /* A: w[s] = exp2(C2*(h.W+b)) — C2 prefolded */ {                          \
      const int4 q0 = *reinterpret_cast<const int4*>(&hcpk[(P)][r_a][0]);      \
      const int4 q1 = *reinterpret_cast<const int4*>(&hcpk[(P)][r_a][4]);      \
      c_old = cq[(P)][wid][kk];   /* D's input, stable since D(t-1) barrier */ \
      float a0 = 0.f, a1 = 0.f;                                                \
      a0 = dot2((unsigned)q0.x, wehs_p[0], a0);                                \
      a1 = dot2((unsigned)q0.y, wehs_p[1], a1);                                \
      a0 = dot2((unsigned)q0.z, wehs_p[2], a0);                                \
      a1 = dot2((unsigned)q0.w, wehs_p[3], a1);                                \
      a0 = dot2((unsigned)q1.x, wehs_p[4], a0);                                \
      a1 = dot2((unsigned)q1.y, wehs_p[5], a1);                                \
      a0 = dot2((unsigned)q1.z, wehs_p[6], a0);                                \
      a1 = dot2((unsigned)q1.w, wehs_p[7], a1);                                \
      float a = a0 + a1;                                                       \
      a = dppadd<0xB1>(a);                                                     \
      a = dppadd<0x4E>(a);                                                     \
      a = dppadd<0x141>(a);                                                    \
      if (r_a == 0) wvm[s_a >> 3][s_a & 7] = fexp2(a + behs_r);                \
    }                                                                          \
    __syncthreads();                                                           \
    int2 hh;                                                                   \
    /* B: e[d] = exp2(L2E*v) — L2E prefolded into mv */ {                      \
      const float4 wa = *reinterpret_cast<const float4*>(&wvm[s_l][0]);        \
      const float4 wb = *reinterpret_cast<const float4*>(&wvm[s_l][4]);        \
      hh = *reinterpret_cast<const int2*>(&hcpk[(P)][cD >> 2][2 * (cD & 3)]);  \
      const f32x2 one2 = {1.f, 1.f};                                           \
      const f32x2 w01 = {wa.x, wa.y}, w23 = {wa.z, wa.w};                      \
      const f32x2 w45 = {wb.x, wb.y}, w67 = {wb.z, wb.w};                      \
      f32x2 ac0 = {0.f, 0.f}, ac0b = {0.f, 0.f};                               \
      f32x2 ac1 = {0.f, 0.f}, ac1b = {0.f, 0.f};                               \
      BSTEP(w01, er2[0], mv[0], ac0);                                          \
      BSTEP(w23, er2[1], mv[1], ac0b);                                         \
      BSTEP(w45, er2[2], mv[2], ac0);                                          \
      BSTEP(w67, er2[3], mv[3], ac0b);                                         \
      BSTEP(w01, er2[4], mv[0], ac1);                                          \
      BSTEP(w23, er2[5], mv[1], ac1b);                                         \
      BSTEP(w45, er2[6], mv[2], ac1);                                          \
      BSTEP(w67, er2[7], mv[3], ac1b);                                         \
      const f32x2 sv0 = ac0 + ac0b;                                            \
      const f32x2 sv1 = ac1 + ac1b;                                            \
      float s0 = sum16(sv0.x + sv0.y);                                         \
      float s1 = sum16(sv1.x + sv1.y);                                         \
      const float e0 = fexp2(s0);                                              \
      const float e1 = fexp2(s1);                                              \
      if (s_l == 0) {                                                          \
        part64[4 * wid + dp] = e0 + e1;                                        \
        xpk[wid][dp] = pkf16(e0 * xv.x, e1 * xv.y);                            \
        *reinterpret_cast<float2*>(&xh[(T)][d0]) =                             \
            make_float2(e0 * xv.x, e1 * xv.y);                                 \
      }                                                                        \
    }                                                                          \
    __syncthreads();                                                           \
    /* D+E: gate dot2 first (no rs dependency), Σe reduce in parallel */ {     \
      const int4 xq = *reinterpret_cast<const int4*>(&xpk[cD][0]);             \
      float sx[4], sh[4];                                                      \
      _Pragma("unroll")                                                        \
      for (int g = 0; g < 4; ++g) {                                            \
        float s = 0.f;                                                         \
        s = dot2((unsigned)xq.x, wx2[4*g],   s);                               \
        s = dot2((unsigned)xq.y, wx2[4*g+1], s);                               \
        s = dot2((unsigned)xq.z, wx2[4*g+2], s);                               \
        s = dot2((unsigned)xq.w, wx2[4*g+3], s);                               \
        sx[g] = s;                                                             \
        float h = 0.f;                                                         \
        h = dot2((unsigned)hh.x, wh2[2*g],   h);                               \
        h = dot2((unsigned)hh.y, wh2[2*g+1], h);                               \
        sh[g] = h;                                                             \
      }                                                                        \
      float tot = part64[lane];                                                \
      tot = sum16(tot);                                                        \
      tot += __int_as_float(__builtin_amdgcn_ds_swizzle(__float_as_int(tot), 0x401F)); \
      tot += __shfl_xor(tot, 32);                                              \
      const float rs = frcp(tot);                                              \
      float ac[4];                                                             \
      _Pragma("unroll")                                                        \
      for (int g = 0; g < 4; ++g) ac[g] = sum16(fmaf(sx[g], rs, sh[g]));       \
      const float gi = ac[0] + b4[0];                                          \
      const float gf = ac[1] + b4[1];                                          \
      const float gG = ac[2] + b4[2];                                          \
      const float go = ac[3] + b4[3];                                          \
      const float si = frcp(1.f + fexp2(-L2E * gi));                           \
      const float sf = frcp(1.f + fexp2(-L2E * gf));                           \
      const float tg = 1.f - 2.f * frcp(1.f + fexp2(C2 * gG));                 \
      const float cn = fmaf(sf, c_old, si * tg);                               \
      const float so = frcp(1.f + fexp2(-L2E * go));                           \
      const float tc = 1.f - 2.f * frcp(1.f + fexp2(C2 * cn));                 \
      const float hn = so * tc;                                                \
      if (cD == 0) {                                                           \
        __half* Hb = reinterpret_cast<__half*>(&hcpk[(P) ^ 1][0][0]);          \
        Hb[(kD >> 4) * 24 + (kD & 15)]       = __float2half_rn(hn);            \
        Hb[(4 + (kD >> 4)) * 24 + (kD & 15)] = __float2half_rn(cn);            \
        cq[(P) ^ 1][wid][kk] = cn;                                             \
        hbuf[(T)][kD] = hn;                                                    \
      }                                                                        \
      if (tid == 0) rsb[(T)] = rs;                                             \
    }                                                                          \
    __syncthreads();                                                           \
  } while (0)

#define BSTEP(W, E, M, ACC) do {                                   \
    f32x2 q_ = __builtin_elementwise_fma(W, E, one2);              \
    f32x2 r_; r_.x = frcp(q_.x); r_.y = frcp(q_.y);                \
    ACC = __builtin_elementwise_fma(M, r_, ACC);                   \
  } while (0)

  for (int t = 0; t < NT; t += 2) {
    STEP(t, 0);
    STEP(t + 1, 1);
  }
#undef BSTEP
#undef STEP

  // ---------------- bulk flush of outputs -----------------------------------
#pragma unroll
  for (int i = 0; i < 4; ++i) {
    const int f = i * 1024 + tid;
    const int t = f >> 5, c = (f & 31) << 2;
    float4 v = *reinterpret_cast<const float4*>(&xh[t][c]);
    const float rs = rsb[t];
    v.x *= rs; v.y *= rs; v.z *= rs; v.w *= rs;
    *reinterpret_cast<float4*>(out + b * (NT * ND) + t * ND + c) = v;
  }
  float* out2 = out + NB * (NT * ND) + b * (NT * NH);
#pragma unroll
  for (int i = 0; i < 2; ++i) {
    const int f = i * 1024 + tid;
    const int t = f >> 4, c = (f & 15) << 2;
    *reinterpret_cast<float4*>(out2 + t * NH + c) =
        *reinterpret_cast<const float4*>(&hbuf[t][c]);
  }
}

extern "C" void kernel_launch(void* const* d_in, const int* in_sizes, int n_in,
                              void* d_out, int out_size, void* d_ws, size_t ws_size,
                              hipStream_t stream) {
  const float* x    = (const float*)d_in[0];
  const float* Wehs = (const float*)d_in[1];
  const float* behs = (const float*)d_in[2];
  const float* Ue   = (const float*)d_in[3];
  const float* Ueb  = (const float*)d_in[4];
  const float* vew  = (const float*)d_in[5];
  // d_in[6] = v_e_b: constant shift before softmax -> no effect, unused.
  const float* Wih  = (const float*)d_in[7];
  const float* Whh  = (const float*)d_in[8];
  const float* bih  = (const float*)d_in[9];
  const float* bhh  = (const float*)d_in[10];
  float* out = (float*)d_out;

  darnn_enc<<<NB, NTH, 0, stream>>>(x, Wehs, behs, Ue, Ueb, vew, Wih, Whh, bih, bhh, out);
}

// Round 14
// 250.530 us; speedup vs baseline: 1.0640x; 1.0326x over previous
//
#include <hip/hip_runtime.h>
#include <hip/hip_bf16.h>
#include <hip/hip_fp16.h>

#define NB 128      // batch
#define NT 128      // Tm1
#define ND 128      // input size (drivers)
#define NH 64       // hidden
#define NTH 1024    // threads per block

typedef float f32x2 __attribute__((ext_vector_type(2)));
typedef _Float16 f16x2 __attribute__((ext_vector_type(2)));

__device__ __forceinline__ float fexp2(float x) { return __builtin_amdgcn_exp2f(x); }
__device__ __forceinline__ float frcp (float x) { return __builtin_amdgcn_rcpf(x); }

template<int CTRL>
__device__ __forceinline__ float dppadd(float v) {
  return v + __int_as_float(__builtin_amdgcn_update_dpp(
      0, __float_as_int(v), CTRL, 0xF, 0xF, true));
}
__device__ __forceinline__ float sum16(float v) {
  v = dppadd<0xB1>(v);   // quad_perm [1,0,3,2]
  v = dppadd<0x4E>(v);   // quad_perm [2,3,0,1]
  v = dppadd<0x141>(v);  // row_half_mirror
  v = dppadd<0x140>(v);  // row_mirror
  return v;
}

// u32 <-> __half2 bit casts
__device__ __forceinline__ __half2 uh(unsigned u) {
  union { unsigned u; __half2 h; } x; x.u = u; return x.h;
}
__device__ __forceinline__ unsigned hu(__half2 h) {
  union { unsigned u; __half2 h; } x; x.h = h; return x.u;
}
__device__ __forceinline__ f16x2 uh2(unsigned u) {
  union { unsigned u; f16x2 h; } x; x.u = u; return x.h;
}
__device__ __forceinline__ unsigned pkf16(float lo, float hi) {
  return hu(__halves2half2(__float2half_rn(lo), __float2half_rn(hi)));
}

// 2-way f16 dot with f32 accumulate: v_dot2_f32_f16 (no unpack glue)
__device__ __forceinline__ float dot2(unsigned a, unsigned b, float c) {
#if __has_builtin(__builtin_amdgcn_fdot2)
  return __builtin_amdgcn_fdot2(uh2(a), uh2(b), c, false);
#else
  const __half2 p = __hmul2(uh(a), uh(b));
  return c + __low2float(p) + __high2float(p);
#endif
}

#define PIN(v) asm volatile("" : "+v"(v))

__global__ __launch_bounds__(NTH)
__attribute__((amdgpu_waves_per_eu(4, 4)))
void darnn_enc(
    const float* __restrict__ x,     // [B][T1][D]
    const float* __restrict__ Wehs,  // [T1][2H]
    const float* __restrict__ behs,  // [T1]
    const float* __restrict__ Ue,    // [T1][T1]
    const float* __restrict__ Ueb,   // [T1]
    const float* __restrict__ vew,   // [T1]
    const float* __restrict__ Wih,   // [4H][D]
    const float* __restrict__ Whh,   // [4H][H]
    const float* __restrict__ bih,   // [256]
    const float* __restrict__ bhh,   // [256]
    float* __restrict__ out)
{
  constexpr float C2  = 2.88539008177792681f;  // 2*log2(e)
  constexpr float L2E = 1.44269504088896340f;  // log2(e)

  __shared__ __align__(16) float          xh[NT][ND];     // 64K: UeT (prologue) -> x -> e*x
  __shared__ __align__(16) float          hbuf[NT][NH];   // 32K: h outputs
  __shared__ __align__(16) unsigned       hcpk[2][8][12]; // [h|c] as half2, dbuf
  __shared__ __align__(16) float          cq[2][16][6];   // c f32 (cell state), dbuf
  __shared__ __align__(16) float          wvm[16][12];    // w_s (L2E-prefolded), 8/row
  __shared__ __align__(16) unsigned       xpk[16][12];    // e*x as half2, 8 vals/row
  __shared__ __align__(16) float          part64[64];     // per-d-pair partial sums of e
  __shared__ __align__(16) float          rsb[NT];        // 1/sum(e) per step

  const int b    = blockIdx.x;
  const int tid  = threadIdx.x;
  const int lane = tid & 63;
  const int wid  = tid >> 6;
  const float* xb = x + b * (NT * ND);

  // phase-B lane decomposition (also drives the prologue compute mapping)
  const int s_l = lane & 15;
  const int dp  = lane >> 4;
  const int d0  = 8 * wid + 2 * dp;

  // ---------------- Prologue stage 1: UeT into xh region --------------------
  // UeT[t][col(s)] = Ue[s][t], col(s) = 64*((s>>2)&1) + 4*(s>>3) + (s&3).
  // Quad-split layout: each lane's 8 s-values = 2 b128 at 2-way banks (free).
  float (*UeT)[ND] = reinterpret_cast<float(*)[ND]>(&xh[0][0]);  // 64KB exact
  {
    const int s_r = tid & 127;
    const int t_q = tid >> 7;          // 0..7
    const int col = 64 * ((s_r >> 2) & 1) + 4 * (s_r >> 3) + (s_r & 3);
#pragma unroll
    for (int i = 0; i < 4; ++i) {
      const int t0 = 4 * (t_q + 8 * i);
      const float4 u4 = *reinterpret_cast<const float4*>(Ue + s_r * NT + t0);
      UeT[t0 + 0][col] = u4.x;
      UeT[t0 + 1][col] = u4.y;
      UeT[t0 + 2][col] = u4.z;
      UeT[t0 + 3][col] = u4.w;
    }
  }
  __syncthreads();

  // ---------------- Prologue stage 2: E -> er2 registers directly -----------
  // Thread (wid,lane) owns exactly its phase-B tile: d in {d0,d0+1}, s in
  // [8*s_l, 8*s_l+8). x read from GLOBAL (L2-resident; LDS unit free for UeT).
  // er2 stays f32 (no bf16 quantization of E anymore).
  f32x2 er2[8];
  {
    const int c0 = 4 * s_l;        // quad 0 (s&7 in 0..3)
    const int c1 = 64 + 4 * s_l;   // quad 1 (s&7 in 4..7)
    const float* xg = xb + d0;
    f32x2 acc2[8];
#pragma unroll
    for (int j = 0; j < 8; ++j) acc2[j] = (f32x2){0.f, 0.f};
    for (int t = 0; t < NT; ++t) {
      const float2 xv2 = *reinterpret_cast<const float2*>(xg + t * ND);
      const float4 u0 = *reinterpret_cast<const float4*>(&UeT[t][c0]);
      const float4 u1 = *reinterpret_cast<const float4*>(&UeT[t][c1]);
      const f32x2 X = {xv2.x, xv2.y};
      acc2[0] = __builtin_elementwise_fma(X, (f32x2){u0.x, u0.x}, acc2[0]);
      acc2[1] = __builtin_elementwise_fma(X, (f32x2){u0.y, u0.y}, acc2[1]);
      acc2[2] = __builtin_elementwise_fma(X, (f32x2){u0.z, u0.z}, acc2[2]);
      acc2[3] = __builtin_elementwise_fma(X, (f32x2){u0.w, u0.w}, acc2[3]);
      acc2[4] = __builtin_elementwise_fma(X, (f32x2){u1.x, u1.x}, acc2[4]);
      acc2[5] = __builtin_elementwise_fma(X, (f32x2){u1.y, u1.y}, acc2[5]);
      acc2[6] = __builtin_elementwise_fma(X, (f32x2){u1.z, u1.z}, acc2[6]);
      acc2[7] = __builtin_elementwise_fma(X, (f32x2){u1.w, u1.w}, acc2[7]);
    }
    const float4 ub0 = *reinterpret_cast<const float4*>(Ueb + 8 * s_l);
    const float4 ub1 = *reinterpret_cast<const float4*>(Ueb + 8 * s_l + 4);
    er2[0] = (f32x2){fexp2(C2 * (acc2[0].x + ub0.x)), fexp2(C2 * (acc2[1].x + ub0.y))};
    er2[1] = (f32x2){fexp2(C2 * (acc2[2].x + ub0.z)), fexp2(C2 * (acc2[3].x + ub0.w))};
    er2[2] = (f32x2){fexp2(C2 * (acc2[4].x + ub1.x)), fexp2(C2 * (acc2[5].x + ub1.y))};
    er2[3] = (f32x2){fexp2(C2 * (acc2[6].x + ub1.z)), fexp2(C2 * (acc2[7].x + ub1.w))};
    er2[4] = (f32x2){fexp2(C2 * (acc2[0].y + ub0.x)), fexp2(C2 * (acc2[1].y + ub0.y))};
    er2[5] = (f32x2){fexp2(C2 * (acc2[2].y + ub0.z)), fexp2(C2 * (acc2[3].y + ub0.w))};
    er2[6] = (f32x2){fexp2(C2 * (acc2[4].y + ub1.x)), fexp2(C2 * (acc2[5].y + ub1.y))};
    er2[7] = (f32x2){fexp2(C2 * (acc2[6].y + ub1.z)), fexp2(C2 * (acc2[7].y + ub1.w))};
  }
  __syncthreads();   // all UeT reads done before x overwrites the region

  // ---------------- stage x into LDS (main-loop input / e*x buffer) ---------
#pragma unroll
  for (int i = 0; i < 4; ++i) {
    const int f = i * 1024 + tid;
    const int t = f >> 5, c = (f & 31) << 2;
    *reinterpret_cast<float4*>(&xh[t][c]) =
        *reinterpret_cast<const float4*>(xb + t * ND + c);
  }

  // zero h/c state (both parities)
  if (tid < 192) (&hcpk[0][0][0])[tid] = 0u;          // half2(0,0)
  if (tid < 192) (&cq[0][0][0])[tid] = 0.f;

  // ---------------- persistent per-thread registers -------------------------
  // phase A: 8 threads per s; C2 folded into weights/bias -> exp2 arg direct
  const int s_a = tid >> 3, r_a = tid & 7;
  unsigned wehs_p[8];
#pragma unroll
  for (int i = 0; i < 4; ++i) {
    const float4 v4 = *reinterpret_cast<const float4*>(Wehs + s_a * 128 + r_a * 16 + 4 * i);
    wehs_p[2*i]   = pkf16(C2 * v4.x, C2 * v4.y);
    wehs_p[2*i+1] = pkf16(C2 * v4.z, C2 * v4.w);
  }
  float behs_r = C2 * behs[s_a];

  // phase B: L2E folded into mv
  f32x2 mv[4];
  {
    const float4 va = *reinterpret_cast<const float4*>(vew + 8 * s_l);
    const float4 vb = *reinterpret_cast<const float4*>(vew + 8 * s_l + 4);
    const float k = -2.f * L2E;
    mv[0] = (f32x2){k * va.x, k * va.y};
    mv[1] = (f32x2){k * va.z, k * va.w};
    mv[2] = (f32x2){k * vb.x, k * vb.y};
    mv[3] = (f32x2){k * vb.z, k * vb.w};
  }

  // phase D+E: lane = 16*kk + cD; unit kD = 4*wid + kk; 4 gates per lane
  const int kk = lane >> 4, cD = lane & 15;
  const int kD = 4 * wid + kk;
  unsigned wx2[16], wh2[8];   // half2-packed gate weights
  float b4[4];
#pragma unroll
  for (int g = 0; g < 4; ++g) {
    const int j = 64 * g + kD;
    const float4 u0 = *reinterpret_cast<const float4*>(Wih + j * 128 + 8 * cD);
    const float4 u1 = *reinterpret_cast<const float4*>(Wih + j * 128 + 8 * cD + 4);
    wx2[4*g]   = pkf16(u0.x, u0.y);
    wx2[4*g+1] = pkf16(u0.z, u0.w);
    wx2[4*g+2] = pkf16(u1.x, u1.y);
    wx2[4*g+3] = pkf16(u1.z, u1.w);
    const float4 u2 = *reinterpret_cast<const float4*>(Whh + j * 64 + 4 * cD);
    wh2[2*g]   = pkf16(u2.x, u2.y);
    wh2[2*g+1] = pkf16(u2.z, u2.w);
    b4[g] = bih[j] + bhh[j];
  }

#pragma unroll
  for (int i = 0; i < 8; ++i) PIN(wehs_p[i]);
#pragma unroll
  for (int i = 0; i < 8; ++i) PIN(er2[i]);
#pragma unroll
  for (int i = 0; i < 4; ++i) PIN(mv[i]);
#pragma unroll
  for (int i = 0; i < 16; ++i) PIN(wx2[i]);
#pragma unroll
  for (int i = 0; i < 8; ++i) PIN(wh2[i]);
#pragma unroll
  for (int g = 0; g < 4; ++g) PIN(b4[g]);
  PIN(behs_r);

  __syncthreads();

  // ---------------- main recurrence: unrolled x2, compile-time parity -------
#define STEP(T, P) do {                                                        \
    const float2 xv = *reinterpret_cast<const float2*>(&xh[(T)][d0]);          \
    float c_old;                                                               \
    /* A: w[s] = exp2(C2*(h.W+b)) — C2 prefolded */ {                          \
      const int4 q0 = *reinterpret_cast<const int4*>(&hcpk[(P)][r_a][0]);      \
      const int4 q1 = *reinterpret_cast<const int4*>(&hcpk[(P)][r_a][4]);      \
      c_old = cq[(P)][wid][kk];   /* D's input, stable since D(t-1) barrier */ \
      float a0 = 0.f, a1 = 0.f;                                                \
      a0 = dot2((unsigned)q0.x, wehs_p[0], a0);                                \
      a1 = dot2((unsigned)q0.y, wehs_p[1], a1);                                \
      a0 = dot2((unsigned)q0.z, wehs_p[2], a0);                                \
      a1 = dot2((unsigned)q0.w, wehs_p[3], a1);                                \
      a0 = dot2((unsigned)q1.x, wehs_p[4], a0);                                \
      a1 = dot2((unsigned)q1.y, wehs_p[5], a1);                                \
      a0 = dot2((unsigned)q1.z, wehs_p[6], a0);                                \
      a1 = dot2((unsigned)q1.w, wehs_p[7], a1);                                \
      float a = a0 + a1;                                                       \
      a = dppadd<0xB1>(a);                                                     \
      a = dppadd<0x4E>(a);                                                     \
      a = dppadd<0x141>(a);                                                    \
      if (r_a == 0) wvm[s_a >> 3][s_a & 7] = fexp2(a + behs_r);                \
    }                                                                          \
    __syncthreads();                                                           \
    int2 hh;                                                                   \
    /* B: e[d] = exp2(L2E*v) — L2E prefolded into mv */ {                      \
      const float4 wa = *reinterpret_cast<const float4*>(&wvm[s_l][0]);        \
      const float4 wb = *reinterpret_cast<const float4*>(&wvm[s_l][4]);        \
      hh = *reinterpret_cast<const int2*>(&hcpk[(P)][cD >> 2][2 * (cD & 3)]);  \
      const f32x2 one2 = {1.f, 1.f};                                           \
      const f32x2 w01 = {wa.x, wa.y}, w23 = {wa.z, wa.w};                      \
      const f32x2 w45 = {wb.x, wb.y}, w67 = {wb.z, wb.w};                      \
      f32x2 ac0 = {0.f, 0.f}, ac0b = {0.f, 0.f};                               \
      f32x2 ac1 = {0.f, 0.f}, ac1b = {0.f, 0.f};                               \
      BSTEP(w01, er2[0], mv[0], ac0);                                          \
      BSTEP(w23, er2[1], mv[1], ac0b);                                         \
      BSTEP(w45, er2[2], mv[2], ac0);                                          \
      BSTEP(w67, er2[3], mv[3], ac0b);                                         \
      BSTEP(w01, er2[4], mv[0], ac1);                                          \
      BSTEP(w23, er2[5], mv[1], ac1b);                                         \
      BSTEP(w45, er2[6], mv[2], ac1);                                          \
      BSTEP(w67, er2[7], mv[3], ac1b);                                         \
      const f32x2 sv0 = ac0 + ac0b;                                            \
      const f32x2 sv1 = ac1 + ac1b;                                            \
      float s0 = sum16(sv0.x + sv0.y);                                         \
      float s1 = sum16(sv1.x + sv1.y);                                         \
      const float e0 = fexp2(s0);                                              \
      const float e1 = fexp2(s1);                                              \
      if (s_l == 0) {                                                          \
        part64[4 * wid + dp] = e0 + e1;                                        \
        xpk[wid][dp] = pkf16(e0 * xv.x, e1 * xv.y);                            \
        *reinterpret_cast<float2*>(&xh[(T)][d0]) =                             \
            make_float2(e0 * xv.x, e1 * xv.y);                                 \
      }                                                                        \
    }                                                                          \
    __syncthreads();                                                           \
    /* D+E: gate dot2 first (no rs dependency), Σe reduce in parallel */ {     \
      const int4 xq = *reinterpret_cast<const int4*>(&xpk[cD][0]);             \
      float sx[4], sh[4];                                                      \
      _Pragma("unroll")                                                        \
      for (int g = 0; g < 4; ++g) {                                            \
        float s = 0.f;                                                         \
        s = dot2((unsigned)xq.x, wx2[4*g],   s);                               \
        s = dot2((unsigned)xq.y, wx2[4*g+1], s);                               \
        s = dot2((unsigned)xq.z, wx2[4*g+2], s);                               \
        s = dot2((unsigned)xq.w, wx2[4*g+3], s);                               \
        sx[g] = s;                                                             \
        float h = 0.f;                                                         \
        h = dot2((unsigned)hh.x, wh2[2*g],   h);                               \
        h = dot2((unsigned)hh.y, wh2[2*g+1], h);                               \
        sh[g] = h;                                                             \
      }                                                                        \
      float tot = part64[lane];                                                \
      tot = sum16(tot);                                                        \
      tot += __int_as_float(__builtin_amdgcn_ds_swizzle(__float_as_int(tot), 0x401F)); \
      tot += __shfl_xor(tot, 32);                                              \
      const float rs = frcp(tot);                                              \
      float ac[4];                                                             \
      _Pragma("unroll")                                                        \
      for (int g = 0; g < 4; ++g) ac[g] = sum16(fmaf(sx[g], rs, sh[g]));       \
      const float gi = ac[0] + b4[0];                                          \
      const float gf = ac[1] + b4[1];                                          \
      const float gG = ac[2] + b4[2];                                          \
      const float go = ac[3] + b4[3];                                          \
      const float si = frcp(1.f + fexp2(-L2E * gi));                           \
      const float sf = frcp(1.f + fexp2(-L2E * gf));                           \
      const float tg = 1.f - 2.f * frcp(1.f + fexp2(C2 * gG));                 \
      const float cn = fmaf(sf, c_old, si * tg);                               \
      const float so = frcp(1.f + fexp2(-L2E * go));                           \
      const float tc = 1.f - 2.f * frcp(1.f + fexp2(C2 * cn));                 \
      const float hn = so * tc;                                                \
      if (cD == 0) {                                                           \
        __half* Hb = reinterpret_cast<__half*>(&hcpk[(P) ^ 1][0][0]);          \
        Hb[(kD >> 4) * 24 + (kD & 15)]       = __float2half_rn(hn);            \
        Hb[(4 + (kD >> 4)) * 24 + (kD & 15)] = __float2half_rn(cn);            \
        cq[(P) ^ 1][wid][kk] = cn;                                             \
        hbuf[(T)][kD] = hn;                                                    \
      }                                                                        \
      if (tid == 0) rsb[(T)] = rs;                                             \
    }                                                                          \
    __syncthreads();                                                           \
  } while (0)

#define BSTEP(W, E, M, ACC) do {                                   \
    f32x2 q_ = __builtin_elementwise_fma(W, E, one2);              \
    f32x2 r_; r_.x = frcp(q_.x); r_.y = frcp(q_.y);                \
    ACC = __builtin_elementwise_fma(M, r_, ACC);                   \
  } while (0)

  for (int t = 0; t < NT; t += 2) {
    STEP(t, 0);
    STEP(t + 1, 1);
  }
#undef BSTEP
#undef STEP

  // ---------------- bulk flush of outputs -----------------------------------
#pragma unroll
  for (int i = 0; i < 4; ++i) {
    const int f = i * 1024 + tid;
    const int t = f >> 5, c = (f & 31) << 2;
    float4 v = *reinterpret_cast<const float4*>(&xh[t][c]);
    const float rs = rsb[t];
    v.x *= rs; v.y *= rs; v.z *= rs; v.w *= rs;
    *reinterpret_cast<float4*>(out + b * (NT * ND) + t * ND + c) = v;
  }
  float* out2 = out + NB * (NT * ND) + b * (NT * NH);
#pragma unroll
  for (int i = 0; i < 2; ++i) {
    const int f = i * 1024 + tid;
    const int t = f >> 4, c = (f & 15) << 2;
    *reinterpret_cast<float4*>(out2 + t * NH + c) =
        *reinterpret_cast<const float4*>(&hbuf[t][c]);
  }
}

extern "C" void kernel_launch(void* const* d_in, const int* in_sizes, int n_in,
                              void* d_out, int out_size, void* d_ws, size_t ws_size,
                              hipStream_t stream) {
  const float* x    = (const float*)d_in[0];
  const float* Wehs = (const float*)d_in[1];
  const float* behs = (const float*)d_in[2];
  const float* Ue   = (const float*)d_in[3];
  const float* Ueb  = (const float*)d_in[4];
  const float* vew  = (const float*)d_in[5];
  // d_in[6] = v_e_b: constant shift before softmax -> no effect, unused.
  const float* Wih  = (const float*)d_in[7];
  const float* Whh  = (const float*)d_in[8];
  const float* bih  = (const float*)d_in[9];
  const float* bhh  = (const float*)d_in[10];
  float* out = (float*)d_out;

  darnn_enc<<<NB, NTH, 0, stream>>>(x, Wehs, behs, Ue, Ueb, vew, Wih, Whh, bih, bhh, out);
}